// Round 1
// baseline (588.720 us; speedup 1.0000x reference)
//
#include <hip/hip_runtime.h>

// ---------- bf16 helpers ----------
__device__ __forceinline__ float bf2f(unsigned short u){
    union { unsigned int i; float f; } v; v.i = ((unsigned int)u) << 16; return v.f;
}
__device__ __forceinline__ unsigned short f2bf(float f){
    union { unsigned int i; float f; } v; v.f = f;
    unsigned int i = v.i;
    unsigned int r = i + 0x7FFFu + ((i >> 16) & 1u);   // round-nearest-even
    return (unsigned short)(r >> 16);
}
__device__ __forceinline__ float sigm(float x){ return 1.0f / (1.0f + __expf(-x)); }

// flag-dispatched scalar load: fF=1 -> fp32, fF=0 -> bf16
__device__ __forceinline__ float ldsel(const void* p, size_t idx, int fF){
    float r;
    if (fF) r = ((const float*)p)[idx];
    else    r = bf2f(((const unsigned short*)p)[idx]);
    return r;
}

typedef __attribute__((ext_vector_type(8))) short s8v;   // 8 bf16 (4 VGPRs)
typedef __attribute__((ext_vector_type(4))) float f4v;   // 4 fp32 accum

// ---------------------------------------------------------------------------
// k_detect: flags[0]=1 if float tensors are fp32 (else bf16);
//           flags[1]=1 if edge_index is int64 (else int32).
__global__ void k_detect(const unsigned short* __restrict__ X,
                         const int* __restrict__ ei, int* __restrict__ flags){
    __shared__ int cnt, nz;
    if (threadIdx.x == 0){ cnt = 0; nz = 0; }
    __syncthreads();
    int ok = 0;
    for (int i = threadIdx.x; i < 2048; i += 256){
        int e = (X[i] >> 7) & 0xFF;
        if (e >= 96 && e <= 160) ok++;
    }
    atomicAdd(&cnt, ok);
    int nzl = 0;
    for (int i = threadIdx.x; i < 128; i += 256)
        if (ei[2*i + 1] != 0) nzl++;
    atomicAdd(&nz, nzl);
    __syncthreads();
    if (threadIdx.x == 0){
        flags[0] = (cnt < 1843) ? 1 : 0;   // <90% plausible-bf16 => fp32
        flags[1] = (nz == 0)   ? 1 : 0;    // all odd int32 words zero => int64
    }
}

// ---------------------------------------------------------------------------
struct PackArgs {
    const void* Wx[4];
    const void* Wh[4];
    const void* bx[4];
    const void* bh[4];
};

// k_fused1: block-range-partitioned independent preamble.
//  blocks [0,nbT):          tobf  — XHb[node][256] bf16 = [X row | H row]
//  blocks [nbT,nbT+nbC):    cnt   — off[e] = cnt[d]++  (the only atomic pass)
//  blocks [nbT+nbC, +512):  pack  — W -> MFMA B lane order; bias = bx+bh
__global__ void k_fused1(const void* __restrict__ X, const void* __restrict__ H,
                         unsigned int* __restrict__ XHb32,
                         const int* __restrict__ ei, int* __restrict__ cnt,
                         int* __restrict__ off,
                         PackArgs pa, unsigned short* __restrict__ Bp,
                         float* __restrict__ bias,
                         const int* __restrict__ flags,
                         int nbT, int nbC, int E, int N){
    int b = blockIdx.x;
    int fF = flags[0];
    if (b < nbT){
        int t = b*256 + threadIdx.x;
        if (t >= N * 64) return;
        int n = t >> 6, l = t & 63;
        unsigned int xw, hw;
        if (fF){
            float2 xv = ((const float2*)X)[(size_t)n*64 + l];
            float2 hv = ((const float2*)H)[(size_t)n*64 + l];
            xw = ((unsigned int)f2bf(xv.y) << 16) | f2bf(xv.x);
            hw = ((unsigned int)f2bf(hv.y) << 16) | f2bf(hv.x);
        } else {
            xw = ((const unsigned int*)X)[(size_t)n*64 + l];
            hw = ((const unsigned int*)H)[(size_t)n*64 + l];
        }
        XHb32[(size_t)n*128 + l]      = xw;
        XHb32[(size_t)n*128 + 64 + l] = hw;
    } else if (b < nbT + nbC){
        int e = (b - nbT)*256 + threadIdx.x;
        if (e >= E) return;
        int fI = flags[1];
        int d = fI ? ei[2*(size_t)E + 2*(size_t)e] : ei[(size_t)E + e];
        if ((unsigned)d >= (unsigned)N) return;
        off[e] = atomicAdd(&cnt[d], 1);
    } else {
        int t = (b - nbT - nbC)*256 + threadIdx.x;
        if (t < 4*8*8*64*8){
            int j    =  t        & 7;
            int lane = (t >> 3)  & 63;
            int kb   = (t >> 9)  & 7;
            int ct   = (t >> 12) & 7;
            int g    = (t >> 15) & 3;
            int k   = kb*32 + (lane >> 4)*8 + j;
            int col = ct*16 + (lane & 15);
            const void* p; size_t idx;
            if (k < 128){ p = pa.Wx[g]; idx = (size_t)k*128 + col; }
            else        { p = pa.Wh[g]; idx = (size_t)(k-128)*128 + col; }
            unsigned short v;
            if (fF) v = f2bf(((const float*)p)[idx]);
            else    v = ((const unsigned short*)p)[idx];
            Bp[t] = v;
        }
        if (t < 512){
            int g = t >> 7, c = t & 127;
            bias[t] = ldsel(pa.bx[g], c, fF) + ldsel(pa.bh[g], c, fF);
        }
    }
}

// ---------------------------------------------------------------------------
// parallel scan trio: rowstart = exclusive_scan(cnt), rowstart[n] = total
__global__ void k_scanA(const int* __restrict__ cnt, int* __restrict__ bsum, int n){
    __shared__ int sh[256];
    int t = threadIdx.x, i = blockIdx.x * 256 + t;
    sh[t] = (i < n) ? cnt[i] : 0;
    __syncthreads();
    for (int o = 128; o > 0; o >>= 1){
        if (t < o) sh[t] += sh[t + o];
        __syncthreads();
    }
    if (t == 0) bsum[blockIdx.x] = sh[0];
}
__global__ void k_scanB(const int* __restrict__ bsum, int* __restrict__ bsumoff, int nb){
    __shared__ int sh[256];
    int t = threadIdx.x;
    int v = (t < nb) ? bsum[t] : 0;
    sh[t] = v;
    __syncthreads();
    for (int o = 1; o < 256; o <<= 1){
        int u = (t >= o) ? sh[t - o] : 0;
        __syncthreads();
        sh[t] += u;
        __syncthreads();
    }
    bsumoff[t] = sh[t] - v;
}
__global__ void k_scanC(const int* __restrict__ cnt, const int* __restrict__ bsumoff,
                        int* __restrict__ rowstart, int n){
    __shared__ int sh[256];
    int t = threadIdx.x, i = blockIdx.x * 256 + t;
    int v = (i < n) ? cnt[i] : 0;
    sh[t] = v;
    __syncthreads();
    for (int o = 1; o < 256; o <<= 1){
        int u = (t >= o) ? sh[t - o] : 0;
        __syncthreads();
        sh[t] += u;
        __syncthreads();
    }
    int incl = sh[t];
    if (i < n)     rowstart[i] = bsumoff[blockIdx.x] + incl - v;
    if (i == n-1)  rowstart[n] = bsumoff[blockIdx.x] + incl;
}

// ---------------------------------------------------------------------------
// k_scatter: recs[rowstart[d]+off[e]] = {src, w}  (no atomics)
__global__ void k_scatter(const int* __restrict__ ei, const void* __restrict__ ew,
                          const int* __restrict__ rowstart, const int* __restrict__ off,
                          int2* __restrict__ recs, const int* __restrict__ flags,
                          int E, int N){
    int e = blockIdx.x * 256 + threadIdx.x;
    if (e >= E) return;
    int fF = flags[0], fI = flags[1];
    int s, d;
    if (fI){ s = ei[2*(size_t)e]; d = ei[2*(size_t)E + 2*(size_t)e]; }
    else   { s = ei[e];           d = ei[(size_t)E + e]; }
    if ((unsigned)d >= (unsigned)N) return;
    float w = 0.f; int ss = 0;
    if ((unsigned)s < (unsigned)N){ w = ldsel(ew, e, fF); ss = s; }
    int2 r; r.x = ss; r.y = __float_as_int(w);
    recs[rowstart[d] + off[e]] = r;
}

// ---------------------------------------------------------------------------
// k_degdis: one wave per node, deg = sum of w over bin (coalesced), dis = rsqrt
__global__ __launch_bounds__(256)
void k_degdis(const int2* __restrict__ recs, const int* __restrict__ rowstart,
              float* __restrict__ dis, int N){
    int gw = (blockIdx.x * 256 + threadIdx.x) >> 6;
    int lane = threadIdx.x & 63;
    if (gw >= N) return;
    int beg = rowstart[gw], end = rowstart[gw + 1];
    float sw = 0.f;
    for (int i = beg + lane; i < end; i += 64) sw += __int_as_float(recs[i].y);
    for (int o = 32; o > 0; o >>= 1) sw += __shfl_down(sw, o);
    if (lane == 0) dis[gw] = (sw > 0.f) ? rsqrtf(sw) : 0.f;
}

// ---------------------------------------------------------------------------
// k_gather: 2 waves per node (wave = one 128-ch half: 0=X, 1=H).
// lane owns 2 channels (one uint of bf16x2). 2-edge unroll for ILP.
__global__ __launch_bounds__(256)
void k_gather(const int2* __restrict__ recs, const int* __restrict__ rowstart,
              const float* __restrict__ dis, const unsigned int* __restrict__ XHb32,
              unsigned int* __restrict__ AXH32, int N){
    int gw = (blockIdx.x * 256 + threadIdx.x) >> 6;
    int lane = threadIdx.x & 63;
    if (gw >= 2*N) return;
    int node = gw >> 1;
    int half = (gw & 1) * 64;
    int beg = rowstart[node], end = rowstart[node + 1];
    float disd = dis[node];
    float a0 = 0.f, a1 = 0.f;
    int i = beg;
    for (; i + 1 < end; i += 2){
        int2 r1 = recs[i];
        int2 r2 = recs[i+1];
        float n1 = dis[r1.x] * __int_as_float(r1.y) * disd;
        float n2 = dis[r2.x] * __int_as_float(r2.y) * disd;
        unsigned int v1 = XHb32[(size_t)r1.x*128 + half + lane];
        unsigned int v2 = XHb32[(size_t)r2.x*128 + half + lane];
        a0 += n1 * bf2f((unsigned short)(v1 & 0xffff));
        a1 += n1 * bf2f((unsigned short)(v1 >> 16));
        a0 += n2 * bf2f((unsigned short)(v2 & 0xffff));
        a1 += n2 * bf2f((unsigned short)(v2 >> 16));
    }
    if (i < end){
        int2 r1 = recs[i];
        float n1 = dis[r1.x] * __int_as_float(r1.y) * disd;
        unsigned int v1 = XHb32[(size_t)r1.x*128 + half + lane];
        a0 += n1 * bf2f((unsigned short)(v1 & 0xffff));
        a1 += n1 * bf2f((unsigned short)(v1 >> 16));
    }
    AXH32[(size_t)node*128 + half + lane] = ((unsigned int)f2bf(a1) << 16) | f2bf(a0);
}

// ---------------------------------------------------------------------------
struct EpiArgs {
    const void *C, *wci, *wcf, *wco, *bi, *bff, *bc, *bo;
};

// Fused GEMM + LSTM epilogue (R3-validated). Block = 4 waves; 16 nodes;
// wave g = gate g. A-fragments loaded directly from AXH (bf16 rows).
__global__ __launch_bounds__(256)
void k_gemm(const unsigned short* __restrict__ AXH,
            const unsigned short* __restrict__ Bp, const float* __restrict__ bias,
            EpiArgs ea, void* __restrict__ outp, const int* __restrict__ flags, int N){
    __shared__ float pre[4][16][132];

    int tid  = threadIdx.x;
    int wave = tid >> 6, lane = tid & 63;
    int node0 = blockIdx.x * 16;
    int fF = flags[0];

    f4v acc[8];
#pragma unroll
    for (int ct = 0; ct < 8; ct++) acc[ct] = (f4v){0.f,0.f,0.f,0.f};

    const int g = wave;
    const unsigned short* abase = AXH + (size_t)(node0 + (lane & 15))*256 + (lane >> 4)*8;
#pragma unroll
    for (int kb = 0; kb < 8; kb++){
        s8v af = *(const s8v*)(abase + kb*32);
        const unsigned short* bbase = Bp + g*32768 + kb*512 + lane*8;
#pragma unroll
        for (int ct = 0; ct < 8; ct++){
            s8v bfrag = *(const s8v*)(bbase + ct*4096);
            acc[ct] = __builtin_amdgcn_mfma_f32_16x16x32_bf16(af, bfrag, acc[ct], 0, 0, 0);
        }
    }

    // D layout: col = lane&15, row = (lane>>4)*4 + r
    int q = lane >> 4, cl = lane & 15;
#pragma unroll
    for (int ct = 0; ct < 8; ct++){
        int col = ct*16 + cl;
        float bv = bias[g*128 + col];
#pragma unroll
        for (int r = 0; r < 4; r++)
            pre[g][q*4 + r][col] = acc[ct][r] + bv;
    }
    __syncthreads();

    // LSTM cell epilogue
    for (int i = tid; i < 2048; i += 256){
        int nn = i >> 7, c = i & 127;
        if (node0 + nn >= N) break;
        size_t gidx = (size_t)(node0+nn)*128 + c;
        float Cv  = ldsel(ea.C, gidx, fF);
        float pi  = pre[0][nn][c], pf = pre[1][nn][c];
        float pcv = pre[2][nn][c], po = pre[3][nn][c];
        float Iv = sigm(pi + ldsel(ea.wci, c, fF)*Cv + ldsel(ea.bi, c, fF));
        float Fv = sigm(pf + ldsel(ea.wcf, c, fF)*Cv + ldsel(ea.bff, c, fF));
        float Tv = tanhf(pcv + ldsel(ea.bc, c, fF));
        float Cn = Fv*Cv + Iv*Tv;
        float Ov = sigm(po + ldsel(ea.wco, c, fF)*Cn + ldsel(ea.bo, c, fF));
        float Hn = Ov * tanhf(Cn);
        if (fF){
            ((float*)outp)[gidx] = Hn;
            ((float*)outp)[(size_t)N*128 + gidx] = Cn;
        } else {
            ((unsigned short*)outp)[gidx] = f2bf(Hn);
            ((unsigned short*)outp)[(size_t)N*128 + gidx] = f2bf(Cn);
        }
    }
}

// ---------------------------------------------------------------------------
extern "C" void kernel_launch(void* const* d_in, const int* in_sizes, int n_in,
                              void* d_out, int out_size, void* d_ws, size_t ws_size,
                              hipStream_t stream){
    const void* X  = d_in[0];
    const int*  ei = (const int*)d_in[1];
    const void* ew = d_in[2];
    const void* H  = d_in[3];
    const void* C  = d_in[4];
    const int N = in_sizes[0] / 128;
    const int E = in_sizes[2];

    // workspace layout (bytes), peak ~66.6 MB:
    // [0,256K) cnt | [256K,512K) dis | [512K,768K) rowstart
    // [768K] bsum(1K) | [772K] bsumoff(1K) | [776K] flags(8B)
    // [1M,1.25M) Bp | [1.25M] bias(2K)
    // [2M,8.4M) off (dead after k_scatter)
    // [2M,27.6M) AXH (aliases off; written by k_gather after scatter)
    // [28M,40.8M) recs | [41M,66.6M) XHb
    char* ws = (char*)d_ws;
    int*   cnt          = (int*)  (ws);
    float* dis          = (float*)(ws + ((size_t)256 << 10));
    int*   rowstart     = (int*)  (ws + ((size_t)512 << 10));
    int*   bsum         = (int*)  (ws + ((size_t)768 << 10));
    int*   bsumoff      = (int*)  (ws + ((size_t)772 << 10));
    int*   flags        = (int*)  (ws + ((size_t)776 << 10));
    unsigned short* Bp  = (unsigned short*)(ws + ((size_t)1 << 20));
    float* bias         = (float*)(ws + ((size_t)1 << 20) + ((size_t)256 << 10));
    int*   off          = (int*)  (ws + ((size_t)2 << 20));
    unsigned int* AXH32 = (unsigned int*)(ws + ((size_t)2 << 20));
    int2*  recs         = (int2*) (ws + ((size_t)28 << 20));
    unsigned int* XHb32 = (unsigned int*)(ws + ((size_t)41 << 20));

    hipMemsetAsync(cnt, 0, (size_t)256 << 10, stream);
    k_detect<<<1, 256, 0, stream>>>((const unsigned short*)X, ei, flags);

    PackArgs pa;
    pa.Wx[0]=d_in[5];  pa.bx[0]=d_in[6];  pa.Wh[0]=d_in[7];  pa.bh[0]=d_in[8];
    pa.Wx[1]=d_in[9];  pa.bx[1]=d_in[10]; pa.Wh[1]=d_in[11]; pa.bh[1]=d_in[12];
    pa.Wx[2]=d_in[13]; pa.bx[2]=d_in[14]; pa.Wh[2]=d_in[15]; pa.bh[2]=d_in[16];
    pa.Wx[3]=d_in[17]; pa.bx[3]=d_in[18]; pa.Wh[3]=d_in[19]; pa.bh[3]=d_in[20];

    int nbT = (N*64 + 255)/256;
    int nbC = (E + 255)/256;
    k_fused1<<<nbT + nbC + 512, 256, 0, stream>>>(X, H, XHb32, ei, cnt, off,
                                                  pa, Bp, bias, flags, nbT, nbC, E, N);

    int nbA = (N + 255)/256;
    k_scanA<<<nbA, 256, 0, stream>>>(cnt, bsum, N);
    k_scanB<<<1, 256, 0, stream>>>(bsum, bsumoff, nbA);
    k_scanC<<<nbA, 256, 0, stream>>>(cnt, bsumoff, rowstart, N);

    k_scatter<<<(E + 255)/256, 256, 0, stream>>>(ei, ew, rowstart, off, recs, flags, E, N);
    k_degdis<<<(N*64 + 255)/256, 256, 0, stream>>>(recs, rowstart, dis, N);
    k_gather<<<(2*N*64 + 255)/256, 256, 0, stream>>>(recs, rowstart, dis, XHb32, AXH32, N);

    EpiArgs ea;
    ea.C   = C;
    ea.wci = d_in[21];
    ea.wcf = d_in[22];
    ea.wco = d_in[23];
    ea.bi  = d_in[24];
    ea.bff = d_in[25];
    ea.bc  = d_in[26];
    ea.bo  = d_in[27];
    k_gemm<<<(N + 15)/16, 256, 0, stream>>>((const unsigned short*)AXH32, Bp, bias,
                                            ea, d_out, flags, N);
}

// Round 2
// 518.870 us; speedup vs baseline: 1.1346x; 1.1346x over previous
//
#include <hip/hip_runtime.h>

// ---------- bf16 helpers ----------
__device__ __forceinline__ float bf2f(unsigned short u){
    union { unsigned int i; float f; } v; v.i = ((unsigned int)u) << 16; return v.f;
}
__device__ __forceinline__ unsigned short f2bf(float f){
    union { unsigned int i; float f; } v; v.f = f;
    unsigned int i = v.i;
    unsigned int r = i + 0x7FFFu + ((i >> 16) & 1u);   // round-nearest-even
    return (unsigned short)(r >> 16);
}
__device__ __forceinline__ float sigm(float x){ return 1.0f / (1.0f + __expf(-x)); }

// flag-dispatched scalar load: fF=1 -> fp32, fF=0 -> bf16
__device__ __forceinline__ float ldsel(const void* p, size_t idx, int fF){
    float r;
    if (fF) r = ((const float*)p)[idx];
    else    r = bf2f(((const unsigned short*)p)[idx]);
    return r;
}

typedef __attribute__((ext_vector_type(8))) short s8v;   // 8 bf16 (4 VGPRs)
typedef __attribute__((ext_vector_type(4))) float f4v;   // 4 fp32 accum

// ---------------------------------------------------------------------------
// k_detect: flags[0]=1 if float tensors are fp32 (else bf16);
//           flags[1]=1 if edge_index is int64 (else int32).
__global__ void k_detect(const unsigned short* __restrict__ X,
                         const int* __restrict__ ei, int* __restrict__ flags){
    __shared__ int cnt, nz;
    if (threadIdx.x == 0){ cnt = 0; nz = 0; }
    __syncthreads();
    int ok = 0;
    for (int i = threadIdx.x; i < 2048; i += 256){
        int e = (X[i] >> 7) & 0xFF;
        if (e >= 96 && e <= 160) ok++;
    }
    atomicAdd(&cnt, ok);
    int nzl = 0;
    for (int i = threadIdx.x; i < 128; i += 256)
        if (ei[2*i + 1] != 0) nzl++;
    atomicAdd(&nz, nzl);
    __syncthreads();
    if (threadIdx.x == 0){
        flags[0] = (cnt < 1843) ? 1 : 0;   // <90% plausible-bf16 => fp32
        flags[1] = (nz == 0)   ? 1 : 0;    // all odd int32 words zero => int64
    }
}

// ---------------------------------------------------------------------------
struct PackArgs {
    const void* Wx[4];
    const void* Wh[4];
    const void* bx[4];
    const void* bh[4];
};

// k_fused1: block-range-partitioned independent preamble.
//  blocks [0,nbT):          tobf  — XHb[node][256] bf16 = [X row | H row]
//  blocks [nbT,nbT+nbC):    cnt   — off[e] = cnt[d]++  (the only atomic pass)
//  blocks [nbT+nbC, +512):  pack  — W -> MFMA B lane order; bias = bx+bh
__global__ void k_fused1(const void* __restrict__ X, const void* __restrict__ H,
                         unsigned int* __restrict__ XHb32,
                         const int* __restrict__ ei, int* __restrict__ cnt,
                         int* __restrict__ off,
                         PackArgs pa, unsigned short* __restrict__ Bp,
                         float* __restrict__ bias,
                         const int* __restrict__ flags,
                         int nbT, int nbC, int E, int N){
    int b = blockIdx.x;
    int fF = flags[0];
    if (b < nbT){
        int t = b*256 + threadIdx.x;
        if (t >= N * 64) return;
        int n = t >> 6, l = t & 63;
        unsigned int xw, hw;
        if (fF){
            float2 xv = ((const float2*)X)[(size_t)n*64 + l];
            float2 hv = ((const float2*)H)[(size_t)n*64 + l];
            xw = ((unsigned int)f2bf(xv.y) << 16) | f2bf(xv.x);
            hw = ((unsigned int)f2bf(hv.y) << 16) | f2bf(hv.x);
        } else {
            xw = ((const unsigned int*)X)[(size_t)n*64 + l];
            hw = ((const unsigned int*)H)[(size_t)n*64 + l];
        }
        XHb32[(size_t)n*128 + l]      = xw;
        XHb32[(size_t)n*128 + 64 + l] = hw;
    } else if (b < nbT + nbC){
        int e = (b - nbT)*256 + threadIdx.x;
        if (e >= E) return;
        int fI = flags[1];
        int d = fI ? ei[2*(size_t)E + 2*(size_t)e] : ei[(size_t)E + e];
        if ((unsigned)d >= (unsigned)N) return;
        off[e] = atomicAdd(&cnt[d], 1);
    } else {
        int t = (b - nbT - nbC)*256 + threadIdx.x;
        if (t < 4*8*8*64*8){
            int j    =  t        & 7;
            int lane = (t >> 3)  & 63;
            int kb   = (t >> 9)  & 7;
            int ct   = (t >> 12) & 7;
            int g    = (t >> 15) & 3;
            int k   = kb*32 + (lane >> 4)*8 + j;
            int col = ct*16 + (lane & 15);
            const void* p; size_t idx;
            if (k < 128){ p = pa.Wx[g]; idx = (size_t)k*128 + col; }
            else        { p = pa.Wh[g]; idx = (size_t)(k-128)*128 + col; }
            unsigned short v;
            if (fF) v = f2bf(((const float*)p)[idx]);
            else    v = ((const unsigned short*)p)[idx];
            Bp[t] = v;
        }
        if (t < 512){
            int g = t >> 7, c = t & 127;
            bias[t] = ldsel(pa.bx[g], c, fF) + ldsel(pa.bh[g], c, fF);
        }
    }
}

// ---------------------------------------------------------------------------
// parallel scan trio: rowstart = exclusive_scan(cnt), rowstart[n] = total
__global__ void k_scanA(const int* __restrict__ cnt, int* __restrict__ bsum, int n){
    __shared__ int sh[256];
    int t = threadIdx.x, i = blockIdx.x * 256 + t;
    sh[t] = (i < n) ? cnt[i] : 0;
    __syncthreads();
    for (int o = 128; o > 0; o >>= 1){
        if (t < o) sh[t] += sh[t + o];
        __syncthreads();
    }
    if (t == 0) bsum[blockIdx.x] = sh[0];
}
__global__ void k_scanB(const int* __restrict__ bsum, int* __restrict__ bsumoff, int nb){
    __shared__ int sh[256];
    int t = threadIdx.x;
    int v = (t < nb) ? bsum[t] : 0;
    sh[t] = v;
    __syncthreads();
    for (int o = 1; o < 256; o <<= 1){
        int u = (t >= o) ? sh[t - o] : 0;
        __syncthreads();
        sh[t] += u;
        __syncthreads();
    }
    bsumoff[t] = sh[t] - v;
}
__global__ void k_scanC(const int* __restrict__ cnt, const int* __restrict__ bsumoff,
                        int* __restrict__ rowstart, int n){
    __shared__ int sh[256];
    int t = threadIdx.x, i = blockIdx.x * 256 + t;
    int v = (i < n) ? cnt[i] : 0;
    sh[t] = v;
    __syncthreads();
    for (int o = 1; o < 256; o <<= 1){
        int u = (t >= o) ? sh[t - o] : 0;
        __syncthreads();
        sh[t] += u;
        __syncthreads();
    }
    int incl = sh[t];
    if (i < n)     rowstart[i] = bsumoff[blockIdx.x] + incl - v;
    if (i == n-1)  rowstart[n] = bsumoff[blockIdx.x] + incl;
}

// ---------------------------------------------------------------------------
// k_scatter: recs[rowstart[d]+off[e]] = {src, w}  (no atomics)
__global__ void k_scatter(const int* __restrict__ ei, const void* __restrict__ ew,
                          const int* __restrict__ rowstart, const int* __restrict__ off,
                          int2* __restrict__ recs, const int* __restrict__ flags,
                          int E, int N){
    int e = blockIdx.x * 256 + threadIdx.x;
    if (e >= E) return;
    int fF = flags[0], fI = flags[1];
    int s, d;
    if (fI){ s = ei[2*(size_t)e]; d = ei[2*(size_t)E + 2*(size_t)e]; }
    else   { s = ei[e];           d = ei[(size_t)E + e]; }
    if ((unsigned)d >= (unsigned)N) return;
    float w = 0.f; int ss = 0;
    if ((unsigned)s < (unsigned)N){ w = ldsel(ew, e, fF); ss = s; }
    int2 r; r.x = ss; r.y = __float_as_int(w);
    recs[rowstart[d] + off[e]] = r;
}

// ---------------------------------------------------------------------------
// k_degdis: one wave per node, deg = sum of w over bin (coalesced), dis = rsqrt
__global__ __launch_bounds__(256)
void k_degdis(const int2* __restrict__ recs, const int* __restrict__ rowstart,
              float* __restrict__ dis, int N){
    int gw = (blockIdx.x * 256 + threadIdx.x) >> 6;
    int lane = threadIdx.x & 63;
    if (gw >= N) return;
    int beg = rowstart[gw], end = rowstart[gw + 1];
    float sw = 0.f;
    for (int i = beg + lane; i < end; i += 64) sw += __int_as_float(recs[i].y);
    for (int o = 32; o > 0; o >>= 1) sw += __shfl_down(sw, o);
    if (lane == 0) dis[gw] = (sw > 0.f) ? rsqrtf(sw) : 0.f;
}

// ---------------------------------------------------------------------------
// k_gather: ONE wave per node; lane owns 4 channels (uint2 of bf16x4).
// 4-edge batched unroll: all recs/dis/XHb loads for the batch issued before
// any consumption -> 4 × 512B row-loads in flight per wave (latency-MLP fix;
// R1: VGPR=12 showed the old 2-wave version had no loads in flight).
__global__ __launch_bounds__(256)
void k_gather(const int2* __restrict__ recs, const int* __restrict__ rowstart,
              const float* __restrict__ dis, const uint2* __restrict__ XHb64,
              uint2* __restrict__ AXH64, int N){
    int node = (blockIdx.x * 256 + threadIdx.x) >> 6;
    int lane = threadIdx.x & 63;
    if (node >= N) return;
    int beg = rowstart[node], end = rowstart[node + 1];
    float disd = dis[node];
    float a0 = 0.f, a1 = 0.f, a2 = 0.f, a3 = 0.f;
    int i = beg;
    for (; i + 3 < end; i += 4){
        int2 r0 = recs[i];
        int2 r1 = recs[i+1];
        int2 r2 = recs[i+2];
        int2 r3 = recs[i+3];
        uint2 v0 = XHb64[(size_t)r0.x*64 + lane];
        uint2 v1 = XHb64[(size_t)r1.x*64 + lane];
        uint2 v2 = XHb64[(size_t)r2.x*64 + lane];
        uint2 v3 = XHb64[(size_t)r3.x*64 + lane];
        float d0 = dis[r0.x];
        float d1 = dis[r1.x];
        float d2 = dis[r2.x];
        float d3 = dis[r3.x];
        float n0 = d0 * __int_as_float(r0.y) * disd;
        float n1 = d1 * __int_as_float(r1.y) * disd;
        float n2 = d2 * __int_as_float(r2.y) * disd;
        float n3 = d3 * __int_as_float(r3.y) * disd;
        a0 += n0 * bf2f((unsigned short)(v0.x & 0xffff));
        a1 += n0 * bf2f((unsigned short)(v0.x >> 16));
        a2 += n0 * bf2f((unsigned short)(v0.y & 0xffff));
        a3 += n0 * bf2f((unsigned short)(v0.y >> 16));
        a0 += n1 * bf2f((unsigned short)(v1.x & 0xffff));
        a1 += n1 * bf2f((unsigned short)(v1.x >> 16));
        a2 += n1 * bf2f((unsigned short)(v1.y & 0xffff));
        a3 += n1 * bf2f((unsigned short)(v1.y >> 16));
        a0 += n2 * bf2f((unsigned short)(v2.x & 0xffff));
        a1 += n2 * bf2f((unsigned short)(v2.x >> 16));
        a2 += n2 * bf2f((unsigned short)(v2.y & 0xffff));
        a3 += n2 * bf2f((unsigned short)(v2.y >> 16));
        a0 += n3 * bf2f((unsigned short)(v3.x & 0xffff));
        a1 += n3 * bf2f((unsigned short)(v3.x >> 16));
        a2 += n3 * bf2f((unsigned short)(v3.y & 0xffff));
        a3 += n3 * bf2f((unsigned short)(v3.y >> 16));
    }
    for (; i < end; i++){
        int2 r0 = recs[i];
        uint2 v0 = XHb64[(size_t)r0.x*64 + lane];
        float n0 = dis[r0.x] * __int_as_float(r0.y) * disd;
        a0 += n0 * bf2f((unsigned short)(v0.x & 0xffff));
        a1 += n0 * bf2f((unsigned short)(v0.x >> 16));
        a2 += n0 * bf2f((unsigned short)(v0.y & 0xffff));
        a3 += n0 * bf2f((unsigned short)(v0.y >> 16));
    }
    uint2 o;
    o.x = ((unsigned int)f2bf(a1) << 16) | f2bf(a0);
    o.y = ((unsigned int)f2bf(a3) << 16) | f2bf(a2);
    AXH64[(size_t)node*64 + lane] = o;
}

// ---------------------------------------------------------------------------
struct EpiArgs {
    const void *C, *wci, *wcf, *wco, *bi, *bff, *bc, *bo;
};

// Fused GEMM + LSTM epilogue (R3-validated). Block = 4 waves; 16 nodes;
// wave g = gate g. A-fragments loaded directly from AXH (bf16 rows).
__global__ __launch_bounds__(256)
void k_gemm(const unsigned short* __restrict__ AXH,
            const unsigned short* __restrict__ Bp, const float* __restrict__ bias,
            EpiArgs ea, void* __restrict__ outp, const int* __restrict__ flags, int N){
    __shared__ float pre[4][16][132];

    int tid  = threadIdx.x;
    int wave = tid >> 6, lane = tid & 63;
    int node0 = blockIdx.x * 16;
    int fF = flags[0];

    f4v acc[8];
#pragma unroll
    for (int ct = 0; ct < 8; ct++) acc[ct] = (f4v){0.f,0.f,0.f,0.f};

    const int g = wave;
    const unsigned short* abase = AXH + (size_t)(node0 + (lane & 15))*256 + (lane >> 4)*8;
#pragma unroll
    for (int kb = 0; kb < 8; kb++){
        s8v af = *(const s8v*)(abase + kb*32);
        const unsigned short* bbase = Bp + g*32768 + kb*512 + lane*8;
#pragma unroll
        for (int ct = 0; ct < 8; ct++){
            s8v bfrag = *(const s8v*)(bbase + ct*4096);
            acc[ct] = __builtin_amdgcn_mfma_f32_16x16x32_bf16(af, bfrag, acc[ct], 0, 0, 0);
        }
    }

    // D layout: col = lane&15, row = (lane>>4)*4 + r
    int q = lane >> 4, cl = lane & 15;
#pragma unroll
    for (int ct = 0; ct < 8; ct++){
        int col = ct*16 + cl;
        float bv = bias[g*128 + col];
#pragma unroll
        for (int r = 0; r < 4; r++)
            pre[g][q*4 + r][col] = acc[ct][r] + bv;
    }
    __syncthreads();

    // LSTM cell epilogue
    for (int i = tid; i < 2048; i += 256){
        int nn = i >> 7, c = i & 127;
        if (node0 + nn >= N) break;
        size_t gidx = (size_t)(node0+nn)*128 + c;
        float Cv  = ldsel(ea.C, gidx, fF);
        float pi  = pre[0][nn][c], pf = pre[1][nn][c];
        float pcv = pre[2][nn][c], po = pre[3][nn][c];
        float Iv = sigm(pi + ldsel(ea.wci, c, fF)*Cv + ldsel(ea.bi, c, fF));
        float Fv = sigm(pf + ldsel(ea.wcf, c, fF)*Cv + ldsel(ea.bff, c, fF));
        float Tv = tanhf(pcv + ldsel(ea.bc, c, fF));
        float Cn = Fv*Cv + Iv*Tv;
        float Ov = sigm(po + ldsel(ea.wco, c, fF)*Cn + ldsel(ea.bo, c, fF));
        float Hn = Ov * tanhf(Cn);
        if (fF){
            ((float*)outp)[gidx] = Hn;
            ((float*)outp)[(size_t)N*128 + gidx] = Cn;
        } else {
            ((unsigned short*)outp)[gidx] = f2bf(Hn);
            ((unsigned short*)outp)[(size_t)N*128 + gidx] = f2bf(Cn);
        }
    }
}

// ---------------------------------------------------------------------------
extern "C" void kernel_launch(void* const* d_in, const int* in_sizes, int n_in,
                              void* d_out, int out_size, void* d_ws, size_t ws_size,
                              hipStream_t stream){
    const void* X  = d_in[0];
    const int*  ei = (const int*)d_in[1];
    const void* ew = d_in[2];
    const void* H  = d_in[3];
    const void* C  = d_in[4];
    const int N = in_sizes[0] / 128;
    const int E = in_sizes[2];

    // workspace layout (bytes), peak ~66.6 MB:
    // [0,256K) cnt | [256K,512K) dis | [512K,768K) rowstart
    // [768K] bsum(1K) | [772K] bsumoff(1K) | [776K] flags(8B)
    // [1M,1.25M) Bp | [1.25M] bias(2K)
    // [2M,8.4M) off (dead after k_scatter)
    // [2M,27.6M) AXH (aliases off; written by k_gather after scatter)
    // [28M,40.8M) recs | [41M,66.6M) XHb
    char* ws = (char*)d_ws;
    int*   cnt          = (int*)  (ws);
    float* dis          = (float*)(ws + ((size_t)256 << 10));
    int*   rowstart     = (int*)  (ws + ((size_t)512 << 10));
    int*   bsum         = (int*)  (ws + ((size_t)768 << 10));
    int*   bsumoff      = (int*)  (ws + ((size_t)772 << 10));
    int*   flags        = (int*)  (ws + ((size_t)776 << 10));
    unsigned short* Bp  = (unsigned short*)(ws + ((size_t)1 << 20));
    float* bias         = (float*)(ws + ((size_t)1 << 20) + ((size_t)256 << 10));
    int*   off          = (int*)  (ws + ((size_t)2 << 20));
    unsigned int* AXH32 = (unsigned int*)(ws + ((size_t)2 << 20));
    int2*  recs         = (int2*) (ws + ((size_t)28 << 20));
    unsigned int* XHb32 = (unsigned int*)(ws + ((size_t)41 << 20));

    hipMemsetAsync(cnt, 0, (size_t)256 << 10, stream);
    k_detect<<<1, 256, 0, stream>>>((const unsigned short*)X, ei, flags);

    PackArgs pa;
    pa.Wx[0]=d_in[5];  pa.bx[0]=d_in[6];  pa.Wh[0]=d_in[7];  pa.bh[0]=d_in[8];
    pa.Wx[1]=d_in[9];  pa.bx[1]=d_in[10]; pa.Wh[1]=d_in[11]; pa.bh[1]=d_in[12];
    pa.Wx[2]=d_in[13]; pa.bx[2]=d_in[14]; pa.Wh[2]=d_in[15]; pa.bh[2]=d_in[16];
    pa.Wx[3]=d_in[17]; pa.bx[3]=d_in[18]; pa.Wh[3]=d_in[19]; pa.bh[3]=d_in[20];

    int nbT = (N*64 + 255)/256;
    int nbC = (E + 255)/256;
    k_fused1<<<nbT + nbC + 512, 256, 0, stream>>>(X, H, XHb32, ei, cnt, off,
                                                  pa, Bp, bias, flags, nbT, nbC, E, N);

    int nbA = (N + 255)/256;
    k_scanA<<<nbA, 256, 0, stream>>>(cnt, bsum, N);
    k_scanB<<<1, 256, 0, stream>>>(bsum, bsumoff, nbA);
    k_scanC<<<nbA, 256, 0, stream>>>(cnt, bsumoff, rowstart, N);

    k_scatter<<<(E + 255)/256, 256, 0, stream>>>(ei, ew, rowstart, off, recs, flags, E, N);
    k_degdis<<<(N*64 + 255)/256, 256, 0, stream>>>(recs, rowstart, dis, N);
    k_gather<<<(N*64 + 255)/256, 256, 0, stream>>>(recs, rowstart, dis,
                                                   (const uint2*)XHb32,
                                                   (uint2*)AXH32, N);

    EpiArgs ea;
    ea.C   = C;
    ea.wci = d_in[21];
    ea.wcf = d_in[22];
    ea.wco = d_in[23];
    ea.bi  = d_in[24];
    ea.bff = d_in[25];
    ea.bc  = d_in[26];
    ea.bo  = d_in[27];
    k_gemm<<<(N + 15)/16, 256, 0, stream>>>((const unsigned short*)AXH32, Bp, bias,
                                            ea, d_out, flags, N);
}

// Round 3
// 501.373 us; speedup vs baseline: 1.1742x; 1.0349x over previous
//
#include <hip/hip_runtime.h>

// ---------- bf16 helpers ----------
__device__ __forceinline__ float bf2f(unsigned short u){
    union { unsigned int i; float f; } v; v.i = ((unsigned int)u) << 16; return v.f;
}
__device__ __forceinline__ unsigned short f2bf(float f){
    union { unsigned int i; float f; } v; v.f = f;
    unsigned int i = v.i;
    unsigned int r = i + 0x7FFFu + ((i >> 16) & 1u);   // round-nearest-even
    return (unsigned short)(r >> 16);
}
__device__ __forceinline__ float sigm(float x){ return 1.0f / (1.0f + __expf(-x)); }

// flag-dispatched scalar load: fF=1 -> fp32, fF=0 -> bf16
__device__ __forceinline__ float ldsel(const void* p, size_t idx, int fF){
    float r;
    if (fF) r = ((const float*)p)[idx];
    else    r = bf2f(((const unsigned short*)p)[idx]);
    return r;
}

typedef __attribute__((ext_vector_type(8))) short s8v;   // 8 bf16 (4 VGPRs)
typedef __attribute__((ext_vector_type(4))) float f4v;   // 4 fp32 accum

// ---------------------------------------------------------------------------
// k_detect: flags[0]=1 if float tensors are fp32 (else bf16);
//           flags[1]=1 if edge_index is int64 (else int32).
__global__ void k_detect(const unsigned short* __restrict__ X,
                         const int* __restrict__ ei, int* __restrict__ flags){
    __shared__ int cnt, nz;
    if (threadIdx.x == 0){ cnt = 0; nz = 0; }
    __syncthreads();
    int ok = 0;
    for (int i = threadIdx.x; i < 2048; i += 256){
        int e = (X[i] >> 7) & 0xFF;
        if (e >= 96 && e <= 160) ok++;
    }
    atomicAdd(&cnt, ok);
    int nzl = 0;
    for (int i = threadIdx.x; i < 128; i += 256)
        if (ei[2*i + 1] != 0) nzl++;
    atomicAdd(&nz, nzl);
    __syncthreads();
    if (threadIdx.x == 0){
        flags[0] = (cnt < 1843) ? 1 : 0;   // <90% plausible-bf16 => fp32
        flags[1] = (nz == 0)   ? 1 : 0;    // all odd int32 words zero => int64
    }
}

// ---------------------------------------------------------------------------
struct PackArgs {
    const void* Wx[4];
    const void* Wh[4];
    const void* bx[4];
    const void* bh[4];
};

// k_fused1: block-range-partitioned independent preamble.
//  blocks [0,nbT):          tobf  — XHb[node][256] bf16 = [X row | H row]
//  blocks [nbT,nbT+nbC):    cnt   — off[e] = cnt[d]++  (the only atomic pass)
//  blocks [nbT+nbC, +512):  pack  — W -> MFMA B lane order; bias = bx+bh
__global__ void k_fused1(const void* __restrict__ X, const void* __restrict__ H,
                         unsigned int* __restrict__ XHb32,
                         const int* __restrict__ ei, int* __restrict__ cnt,
                         int* __restrict__ off,
                         PackArgs pa, unsigned short* __restrict__ Bp,
                         float* __restrict__ bias,
                         const int* __restrict__ flags,
                         int nbT, int nbC, int E, int N){
    int b = blockIdx.x;
    int fF = flags[0];
    if (b < nbT){
        int t = b*256 + threadIdx.x;
        if (t >= N * 64) return;
        int n = t >> 6, l = t & 63;
        unsigned int xw, hw;
        if (fF){
            float2 xv = ((const float2*)X)[(size_t)n*64 + l];
            float2 hv = ((const float2*)H)[(size_t)n*64 + l];
            xw = ((unsigned int)f2bf(xv.y) << 16) | f2bf(xv.x);
            hw = ((unsigned int)f2bf(hv.y) << 16) | f2bf(hv.x);
        } else {
            xw = ((const unsigned int*)X)[(size_t)n*64 + l];
            hw = ((const unsigned int*)H)[(size_t)n*64 + l];
        }
        XHb32[(size_t)n*128 + l]      = xw;
        XHb32[(size_t)n*128 + 64 + l] = hw;
    } else if (b < nbT + nbC){
        int e = (b - nbT)*256 + threadIdx.x;
        if (e >= E) return;
        int fI = flags[1];
        int d = fI ? ei[2*(size_t)E + 2*(size_t)e] : ei[(size_t)E + e];
        if ((unsigned)d >= (unsigned)N) return;
        off[e] = atomicAdd(&cnt[d], 1);
    } else {
        int t = (b - nbT - nbC)*256 + threadIdx.x;
        if (t < 4*8*8*64*8){
            int j    =  t        & 7;
            int lane = (t >> 3)  & 63;
            int kb   = (t >> 9)  & 7;
            int ct   = (t >> 12) & 7;
            int g    = (t >> 15) & 3;
            int k   = kb*32 + (lane >> 4)*8 + j;
            int col = ct*16 + (lane & 15);
            const void* p; size_t idx;
            if (k < 128){ p = pa.Wx[g]; idx = (size_t)k*128 + col; }
            else        { p = pa.Wh[g]; idx = (size_t)(k-128)*128 + col; }
            unsigned short v;
            if (fF) v = f2bf(((const float*)p)[idx]);
            else    v = ((const unsigned short*)p)[idx];
            Bp[t] = v;
        }
        if (t < 512){
            int g = t >> 7, c = t & 127;
            bias[t] = ldsel(pa.bx[g], c, fF) + ldsel(pa.bh[g], c, fF);
        }
    }
}

// ---------------------------------------------------------------------------
// parallel scan trio: rowstart = exclusive_scan(cnt), rowstart[n] = total
__global__ void k_scanA(const int* __restrict__ cnt, int* __restrict__ bsum, int n){
    __shared__ int sh[256];
    int t = threadIdx.x, i = blockIdx.x * 256 + t;
    sh[t] = (i < n) ? cnt[i] : 0;
    __syncthreads();
    for (int o = 128; o > 0; o >>= 1){
        if (t < o) sh[t] += sh[t + o];
        __syncthreads();
    }
    if (t == 0) bsum[blockIdx.x] = sh[0];
}
__global__ void k_scanB(const int* __restrict__ bsum, int* __restrict__ bsumoff, int nb){
    __shared__ int sh[256];
    int t = threadIdx.x;
    int v = (t < nb) ? bsum[t] : 0;
    sh[t] = v;
    __syncthreads();
    for (int o = 1; o < 256; o <<= 1){
        int u = (t >= o) ? sh[t - o] : 0;
        __syncthreads();
        sh[t] += u;
        __syncthreads();
    }
    bsumoff[t] = sh[t] - v;
}
__global__ void k_scanC(const int* __restrict__ cnt, const int* __restrict__ bsumoff,
                        int* __restrict__ rowstart, int n){
    __shared__ int sh[256];
    int t = threadIdx.x, i = blockIdx.x * 256 + t;
    int v = (i < n) ? cnt[i] : 0;
    sh[t] = v;
    __syncthreads();
    for (int o = 1; o < 256; o <<= 1){
        int u = (t >= o) ? sh[t - o] : 0;
        __syncthreads();
        sh[t] += u;
        __syncthreads();
    }
    int incl = sh[t];
    if (i < n)     rowstart[i] = bsumoff[blockIdx.x] + incl - v;
    if (i == n-1)  rowstart[n] = bsumoff[blockIdx.x] + incl;
}

// ---------------------------------------------------------------------------
// k_scatter: recs[rowstart[d]+off[e]] = {src, w}  (no atomics)
__global__ void k_scatter(const int* __restrict__ ei, const void* __restrict__ ew,
                          const int* __restrict__ rowstart, const int* __restrict__ off,
                          int2* __restrict__ recs, const int* __restrict__ flags,
                          int E, int N){
    int e = blockIdx.x * 256 + threadIdx.x;
    if (e >= E) return;
    int fF = flags[0], fI = flags[1];
    int s, d;
    if (fI){ s = ei[2*(size_t)e]; d = ei[2*(size_t)E + 2*(size_t)e]; }
    else   { s = ei[e];           d = ei[(size_t)E + e]; }
    if ((unsigned)d >= (unsigned)N) return;
    float w = 0.f; int ss = 0;
    if ((unsigned)s < (unsigned)N){ w = ldsel(ew, e, fF); ss = s; }
    int2 r; r.x = ss; r.y = __float_as_int(w);
    recs[rowstart[d] + off[e]] = r;
}

// ---------------------------------------------------------------------------
// k_degdis: one wave per node, deg = sum of w over bin (coalesced), dis = rsqrt
__global__ __launch_bounds__(256)
void k_degdis(const int2* __restrict__ recs, const int* __restrict__ rowstart,
              float* __restrict__ dis, int N){
    int gw = (blockIdx.x * 256 + threadIdx.x) >> 6;
    int lane = threadIdx.x & 63;
    if (gw >= N) return;
    int beg = rowstart[gw], end = rowstart[gw + 1];
    float sw = 0.f;
    for (int i = beg + lane; i < end; i += 64) sw += __int_as_float(recs[i].y);
    for (int o = 32; o > 0; o >>= 1) sw += __shfl_down(sw, o);
    if (lane == 0) dis[gw] = (sw > 0.f) ? rsqrtf(sw) : 0.f;
}

// ---------------------------------------------------------------------------
// k_gather v3: ONE wave per node; lane-pair edges — lanes 0-31 do edge i,
// lanes 32-63 do edge i+1; each lane loads uint4 (16B) so one load instr
// covers 2 full 512B rows. x2 unroll = 4 edges in flight per iteration.
// Cross-half partials merged with 8 shfl_xor(32) at loop end (once/node).
__global__ __launch_bounds__(256)
void k_gather(const int2* __restrict__ recs, const int* __restrict__ rowstart,
              const float* __restrict__ dis, const uint4* __restrict__ XHb128,
              uint4* __restrict__ AXH128, int N){
    int node = (blockIdx.x * 256 + threadIdx.x) >> 6;
    int lane = threadIdx.x & 63;
    if (node >= N) return;
    int half = lane >> 5;      // edge of the pair
    int sub  = lane & 31;      // 16B chunk within row
    int beg = rowstart[node], end = rowstart[node + 1];
    float disd = dis[node];
    float a0=0.f,a1=0.f,a2=0.f,a3=0.f,a4=0.f,a5=0.f,a6=0.f,a7=0.f;

#define ACC8(v, n)                                              \
    a0 += (n) * bf2f((unsigned short)((v).x & 0xffff));         \
    a1 += (n) * bf2f((unsigned short)((v).x >> 16));            \
    a2 += (n) * bf2f((unsigned short)((v).y & 0xffff));         \
    a3 += (n) * bf2f((unsigned short)((v).y >> 16));            \
    a4 += (n) * bf2f((unsigned short)((v).z & 0xffff));         \
    a5 += (n) * bf2f((unsigned short)((v).z >> 16));            \
    a6 += (n) * bf2f((unsigned short)((v).w & 0xffff));         \
    a7 += (n) * bf2f((unsigned short)((v).w >> 16));

    int i = beg;
    for (; i + 3 < end; i += 4){
        int2 rA = recs[i + half];
        int2 rB = recs[i + 2 + half];
        uint4 vA = XHb128[(size_t)rA.x*32 + sub];
        uint4 vB = XHb128[(size_t)rB.x*32 + sub];
        float nA = dis[rA.x] * __int_as_float(rA.y) * disd;
        float nB = dis[rB.x] * __int_as_float(rB.y) * disd;
        ACC8(vA, nA);
        ACC8(vB, nB);
    }
    if (end - i >= 2){
        int2 rA = recs[i + half];
        uint4 vA = XHb128[(size_t)rA.x*32 + sub];
        float nA = dis[rA.x] * __int_as_float(rA.y) * disd;
        ACC8(vA, nA);
        i += 2;
    }
    if (i < end){   // one edge left: both halves read it, half 1 contributes 0
        int2 rA = recs[i];
        uint4 vA = XHb128[(size_t)rA.x*32 + sub];
        float nA = (half == 0) ? dis[rA.x] * __int_as_float(rA.y) * disd : 0.f;
        ACC8(vA, nA);
    }
#undef ACC8

    a0 += __shfl_xor(a0, 32, 64);
    a1 += __shfl_xor(a1, 32, 64);
    a2 += __shfl_xor(a2, 32, 64);
    a3 += __shfl_xor(a3, 32, 64);
    a4 += __shfl_xor(a4, 32, 64);
    a5 += __shfl_xor(a5, 32, 64);
    a6 += __shfl_xor(a6, 32, 64);
    a7 += __shfl_xor(a7, 32, 64);

    if (half == 0){
        uint4 o;
        o.x = ((unsigned int)f2bf(a1) << 16) | f2bf(a0);
        o.y = ((unsigned int)f2bf(a3) << 16) | f2bf(a2);
        o.z = ((unsigned int)f2bf(a5) << 16) | f2bf(a4);
        o.w = ((unsigned int)f2bf(a7) << 16) | f2bf(a6);
        AXH128[(size_t)node*32 + sub] = o;
    }
}

// ---------------------------------------------------------------------------
struct EpiArgs {
    const void *C, *wci, *wcf, *wco, *bi, *bff, *bc, *bo;
};

// k_gemm v2: 32 nodes/block (2 M-tiles), 4 waves; wave w owns channel slice
// [w*32, w*32+32) of ALL FOUR gates -> LSTM epilogue fully in-register
// (no LDS, no syncthreads). Bp per-block L2 traffic halved vs 16-node blocks.
__global__ __launch_bounds__(256)
void k_gemm(const unsigned short* __restrict__ AXH,
            const unsigned short* __restrict__ Bp, const float* __restrict__ bias,
            EpiArgs ea, void* __restrict__ outp, const int* __restrict__ flags, int N){
    int tid  = threadIdx.x;
    int w    = tid >> 6, lane = tid & 63;
    int node0 = blockIdx.x * 32;
    int fF = flags[0];

    // acc[m][ct8]: m = M-tile (16 nodes), ct8 = g*2+sub (gate g, 16-col half sub)
    f4v acc[2][8];
#pragma unroll
    for (int m = 0; m < 2; m++)
#pragma unroll
        for (int c = 0; c < 8; c++) acc[m][c] = (f4v){0.f,0.f,0.f,0.f};

    const unsigned short* a0base = AXH + (size_t)(node0 + (lane & 15))*256 + (lane >> 4)*8;
    const unsigned short* a1base = a0base + 16*256;
#pragma unroll
    for (int kb = 0; kb < 8; kb++){
        s8v af0 = *(const s8v*)(a0base + kb*32);
        s8v af1 = *(const s8v*)(a1base + kb*32);
#pragma unroll
        for (int ct8 = 0; ct8 < 8; ct8++){
            int g = ct8 >> 1, sub = ct8 & 1;
            const s8v bfrag = *(const s8v*)(Bp + g*32768 + (size_t)(w*2 + sub)*4096
                                            + kb*512 + lane*8);
            acc[0][ct8] = __builtin_amdgcn_mfma_f32_16x16x32_bf16(af0, bfrag, acc[0][ct8], 0, 0, 0);
            acc[1][ct8] = __builtin_amdgcn_mfma_f32_16x16x32_bf16(af1, bfrag, acc[1][ct8], 0, 0, 0);
        }
    }

    // D layout: col = lane&15 (within 16-col tile), row = (lane>>4)*4 + r
    int q = lane >> 4, cl = lane & 15;
#pragma unroll
    for (int sub = 0; sub < 2; sub++){
        int c = w*32 + sub*16 + cl;            // channel in [0,128)
        float bvi = bias[0*128 + c], bvf = bias[1*128 + c];
        float bvc = bias[2*128 + c], bvo = bias[3*128 + c];
        float wci = ldsel(ea.wci, c, fF), wcf = ldsel(ea.wcf, c, fF), wco = ldsel(ea.wco, c, fF);
        float bi  = ldsel(ea.bi, c, fF),  bff = ldsel(ea.bff, c, fF);
        float bc  = ldsel(ea.bc, c, fF),  bo  = ldsel(ea.bo, c, fF);
#pragma unroll
        for (int m = 0; m < 2; m++){
#pragma unroll
            for (int r = 0; r < 4; r++){
                int node = node0 + m*16 + q*4 + r;
                if (node >= N) continue;
                size_t gidx = (size_t)node*128 + c;
                float Cv = ldsel(ea.C, gidx, fF);
                float pi  = acc[m][0+sub][r] + bvi;
                float pf  = acc[m][2+sub][r] + bvf;
                float pcv = acc[m][4+sub][r] + bvc;
                float po  = acc[m][6+sub][r] + bvo;
                float Iv = sigm(pi + wci*Cv + bi);
                float Fv = sigm(pf + wcf*Cv + bff);
                float Tv = tanhf(pcv + bc);
                float Cn = Fv*Cv + Iv*Tv;
                float Ov = sigm(po + wco*Cn + bo);
                float Hn = Ov * tanhf(Cn);
                if (fF){
                    ((float*)outp)[gidx] = Hn;
                    ((float*)outp)[(size_t)N*128 + gidx] = Cn;
                } else {
                    ((unsigned short*)outp)[gidx] = f2bf(Hn);
                    ((unsigned short*)outp)[(size_t)N*128 + gidx] = f2bf(Cn);
                }
            }
        }
    }
}

// ---------------------------------------------------------------------------
extern "C" void kernel_launch(void* const* d_in, const int* in_sizes, int n_in,
                              void* d_out, int out_size, void* d_ws, size_t ws_size,
                              hipStream_t stream){
    const void* X  = d_in[0];
    const int*  ei = (const int*)d_in[1];
    const void* ew = d_in[2];
    const void* H  = d_in[3];
    const void* C  = d_in[4];
    const int N = in_sizes[0] / 128;
    const int E = in_sizes[2];

    // workspace layout (bytes), peak ~66.6 MB:
    // [0,256K) cnt | [256K,512K) dis | [512K,768K) rowstart
    // [768K] bsum(1K) | [772K] bsumoff(1K) | [776K] flags(8B)
    // [1M,1.25M) Bp | [1.25M] bias(2K)
    // [2M,8.4M) off (dead after k_scatter)
    // [2M,27.6M) AXH (aliases off; written by k_gather after scatter)
    // [28M,40.8M) recs | [41M,66.6M) XHb
    char* ws = (char*)d_ws;
    int*   cnt          = (int*)  (ws);
    float* dis          = (float*)(ws + ((size_t)256 << 10));
    int*   rowstart     = (int*)  (ws + ((size_t)512 << 10));
    int*   bsum         = (int*)  (ws + ((size_t)768 << 10));
    int*   bsumoff      = (int*)  (ws + ((size_t)772 << 10));
    int*   flags        = (int*)  (ws + ((size_t)776 << 10));
    unsigned short* Bp  = (unsigned short*)(ws + ((size_t)1 << 20));
    float* bias         = (float*)(ws + ((size_t)1 << 20) + ((size_t)256 << 10));
    int*   off          = (int*)  (ws + ((size_t)2 << 20));
    unsigned int* AXH32 = (unsigned int*)(ws + ((size_t)2 << 20));
    int2*  recs         = (int2*) (ws + ((size_t)28 << 20));
    unsigned int* XHb32 = (unsigned int*)(ws + ((size_t)41 << 20));

    hipMemsetAsync(cnt, 0, (size_t)256 << 10, stream);
    k_detect<<<1, 256, 0, stream>>>((const unsigned short*)X, ei, flags);

    PackArgs pa;
    pa.Wx[0]=d_in[5];  pa.bx[0]=d_in[6];  pa.Wh[0]=d_in[7];  pa.bh[0]=d_in[8];
    pa.Wx[1]=d_in[9];  pa.bx[1]=d_in[10]; pa.Wh[1]=d_in[11]; pa.bh[1]=d_in[12];
    pa.Wx[2]=d_in[13]; pa.bx[2]=d_in[14]; pa.Wh[2]=d_in[15]; pa.bh[2]=d_in[16];
    pa.Wx[3]=d_in[17]; pa.bx[3]=d_in[18]; pa.Wh[3]=d_in[19]; pa.bh[3]=d_in[20];

    int nbT = (N*64 + 255)/256;
    int nbC = (E + 255)/256;
    k_fused1<<<nbT + nbC + 512, 256, 0, stream>>>(X, H, XHb32, ei, cnt, off,
                                                  pa, Bp, bias, flags, nbT, nbC, E, N);

    int nbA = (N + 255)/256;
    k_scanA<<<nbA, 256, 0, stream>>>(cnt, bsum, N);
    k_scanB<<<1, 256, 0, stream>>>(bsum, bsumoff, nbA);
    k_scanC<<<nbA, 256, 0, stream>>>(cnt, bsumoff, rowstart, N);

    k_scatter<<<(E + 255)/256, 256, 0, stream>>>(ei, ew, rowstart, off, recs, flags, E, N);
    k_degdis<<<(N*64 + 255)/256, 256, 0, stream>>>(recs, rowstart, dis, N);
    k_gather<<<(N*64 + 255)/256, 256, 0, stream>>>(recs, rowstart, dis,
                                                   (const uint4*)XHb32,
                                                   (uint4*)AXH32, N);

    EpiArgs ea;
    ea.C   = C;
    ea.wci = d_in[21];
    ea.wcf = d_in[22];
    ea.wco = d_in[23];
    ea.bi  = d_in[24];
    ea.bff = d_in[25];
    ea.bc  = d_in[26];
    ea.bo  = d_in[27];
    k_gemm<<<(N + 31)/32, 256, 0, stream>>>((const unsigned short*)AXH32, Bp, bias,
                                            ea, d_out, flags, N);
}